// Round 1
// baseline (4982.941 us; speedup 1.0000x reference)
//
#include <hip/hip_runtime.h>
#include <math.h>

#define BATCH 64
#define TLEN 512
#define EMB 256
#define HID 256          // per-direction hidden
#define G4 1024          // 4*HID
#define KTAG 12
#define START_TAG 10
#define STOP_TAG 11
#define NEGV -10000.0f

// ---------------------------------------------------------------------------
// K0: pack W_hh (both dirs) into Wp[d][k][j] = float4{Wi[j,k],Wf[j,k],Wg[j,k],Wo[j,k]}
// so the scan kernel reads one coalesced float4 per (k, j).
// ---------------------------------------------------------------------------
__global__ __launch_bounds__(256) void pack_whh(const float* __restrict__ Wf,
                                                const float* __restrict__ Wb,
                                                float4* __restrict__ Wp) {
    int idx = blockIdx.x * 256 + threadIdx.x;      // 0..131071
    int d   = idx >> 16;
    int rem = idx & 65535;
    int j   = rem >> 8;      // hidden dim
    int k   = rem & 255;     // contraction dim (fast -> coalesced reads)
    const float* W = d ? Wb : Wf;
    float4 v;
    v.x = W[(size_t)(j          ) * HID + k];
    v.y = W[(size_t)(j +     HID) * HID + k];
    v.z = W[(size_t)(j + 2 * HID) * HID + k];
    v.w = W[(size_t)(j + 3 * HID) * HID + k];
    Wp[(size_t)d * 65536 + (size_t)k * 256 + j] = v;
}

// ---------------------------------------------------------------------------
// K1: fused embedding gather + input projection, both directions.
// C[r][g2] = emb[token[r]] . W_ih[g2] + b_ih[g2] + b_hh[g2]
// r = b*512+t (M=32768), g2 in [0,2048): [Wf rows | Wb rows]
// 128x128 tile, 256 threads, 8x8 microtile, fp32.
// ---------------------------------------------------------------------------
#define MT 128
#define NT 128
#define KC 32
#define LDP 132   // padded row (multiple of 4 for b128 alignment)

__global__ __launch_bounds__(256) void proj_kernel(
    const int* __restrict__ sentence, const float* __restrict__ emb,
    const float* __restrict__ Wf_ih, const float* __restrict__ Wb_ih,
    const float* __restrict__ bf_ih, const float* __restrict__ bf_hh,
    const float* __restrict__ bb_ih, const float* __restrict__ bb_hh,
    float* __restrict__ xf, float* __restrict__ xb) {
    int mtile = blockIdx.x;           // 0..255
    int ntile = blockIdx.y;           // 0..15
    int tid = threadIdx.x;

    __shared__ float As[KC][LDP];
    __shared__ float Bs[KC][LDP];
    __shared__ int tok[MT];

    int g2base = ntile * NT;
    const bool fwd = (g2base < 1024);
    const float* Wih = fwd ? Wf_ih : Wb_ih;
    const float* bia = fwd ? bf_ih : bb_ih;
    const float* bib = fwd ? bf_hh : bb_hh;
    float* dst       = fwd ? xf    : xb;
    int glb = g2base & 1023;

    if (tid < MT) tok[tid] = sentence[(size_t)mtile * MT + tid];
    __syncthreads();

    float acc[8][8];
#pragma unroll
    for (int i = 0; i < 8; ++i)
#pragma unroll
        for (int jj = 0; jj < 8; ++jj) acc[i][jj] = 0.f;

    int m0 = (tid & 15) * 8;
    int n0 = (tid >> 4) * 8;
    int lr = tid >> 3;          // 0..31
    int lk = (tid & 7) * 4;     // 0..28

    for (int k0 = 0; k0 < EMB; k0 += KC) {
#pragma unroll
        for (int i = 0; i < 4; ++i) {
            int r = lr + 32 * i;
            float4 v = *(const float4*)(emb + (size_t)tok[r] * EMB + k0 + lk);
            As[lk + 0][r] = v.x; As[lk + 1][r] = v.y;
            As[lk + 2][r] = v.z; As[lk + 3][r] = v.w;
            float4 w = *(const float4*)(Wih + (size_t)(glb + r) * EMB + k0 + lk);
            Bs[lk + 0][r] = w.x; Bs[lk + 1][r] = w.y;
            Bs[lk + 2][r] = w.z; Bs[lk + 3][r] = w.w;
        }
        __syncthreads();
#pragma unroll
        for (int kk = 0; kk < KC; ++kk) {
            float4 a0 = *(const float4*)&As[kk][m0];
            float4 a1 = *(const float4*)&As[kk][m0 + 4];
            float4 b0 = *(const float4*)&Bs[kk][n0];
            float4 b1 = *(const float4*)&Bs[kk][n0 + 4];
            float av[8] = {a0.x, a0.y, a0.z, a0.w, a1.x, a1.y, a1.z, a1.w};
            float bv[8] = {b0.x, b0.y, b0.z, b0.w, b1.x, b1.y, b1.z, b1.w};
#pragma unroll
            for (int i = 0; i < 8; ++i)
#pragma unroll
                for (int jj = 0; jj < 8; ++jj) acc[i][jj] += av[i] * bv[jj];
        }
        __syncthreads();
    }

#pragma unroll
    for (int jj = 0; jj < 8; ++jj) {
        int gl = glb + n0 + jj;
        float bias = bia[gl] + bib[gl];
#pragma unroll
        for (int i = 0; i < 8; ++i) {
            size_t r = (size_t)mtile * MT + m0 + i;
            dst[r * (size_t)G4 + gl] = acc[i][jj] + bias;
        }
    }
}

// ---------------------------------------------------------------------------
// K2: LSTM scan. One block per (dir, batch): 128 blocks x 256 threads.
// Thread j owns hidden dim j: computes i,f,g,o dots (256 each) per step.
// W streamed from L2 (1 MB/step/block) -- round-1 bottleneck by design.
// ---------------------------------------------------------------------------
__global__ __launch_bounds__(256) void lstm_scan(
    const float* __restrict__ xf, const float* __restrict__ xb,
    const float4* __restrict__ Wp, float* __restrict__ hcat) {
    int blk = blockIdx.x;
    int d = blk >> 6;          // 0=fwd, 1=bwd
    int b = blk & 63;
    int j = threadIdx.x;       // hidden dim

    const float* x = (d ? xb : xf) + (size_t)b * TLEN * G4;
    const float4* W = Wp + (size_t)d * 65536;

    __shared__ float hs[HID];
    hs[j] = 0.f;
    float c = 0.f;
    __syncthreads();

    for (int s = 0; s < TLEN; ++s) {
        int t = d ? (TLEN - 1 - s) : s;
        const float* xt = x + (size_t)t * G4;
        float4 acc;
        acc.x = xt[j];
        acc.y = xt[j + 256];
        acc.z = xt[j + 512];
        acc.w = xt[j + 768];
#pragma unroll 8
        for (int k = 0; k < HID; ++k) {
            float hk = hs[k];
            float4 w = W[k * 256 + j];
            acc.x += w.x * hk;
            acc.y += w.y * hk;
            acc.z += w.z * hk;
            acc.w += w.w * hk;
        }
        float ig = 1.f / (1.f + expf(-acc.x));
        float fg = 1.f / (1.f + expf(-acc.y));
        float gg = tanhf(acc.z);
        float og = 1.f / (1.f + expf(-acc.w));
        c = fg * c + ig * gg;
        float h = og * tanhf(c);
        __syncthreads();           // all done reading hs(t-1)
        hs[j] = h;
        __syncthreads();
        hcat[((size_t)t * BATCH + b) * 512 + (size_t)d * HID + j] = h;
    }
}

// ---------------------------------------------------------------------------
// K3: feats[t,b,k] = hcat[t,b,:] . W_out[k,:] + b_out[k].  One wave per row.
// ---------------------------------------------------------------------------
__global__ __launch_bounds__(256) void feats_kernel(
    const float* __restrict__ hcat, const float* __restrict__ Wout,
    const float* __restrict__ bout, float* __restrict__ feats) {
    int wid = threadIdx.x >> 6;
    int lane = threadIdx.x & 63;
    size_t row = (size_t)blockIdx.x * 4 + wid;   // t*64+b, 32768 rows
    const float* hrow = hcat + row * 512;
    float4 h0 = *(const float4*)(hrow + lane * 8);
    float4 h1 = *(const float4*)(hrow + lane * 8 + 4);
    for (int k2 = 0; k2 < KTAG; ++k2) {
        const float* wr = Wout + (size_t)k2 * 512 + lane * 8;
        float4 w0 = *(const float4*)wr;
        float4 w1 = *(const float4*)(wr + 4);
        float p = h0.x * w0.x + h0.y * w0.y + h0.z * w0.z + h0.w * w0.w
                + h1.x * w1.x + h1.y * w1.y + h1.z * w1.z + h1.w * w1.w;
#pragma unroll
        for (int off = 32; off; off >>= 1) p += __shfl_down(p, off);
        if (lane == 0) feats[row * KTAG + k2] = p + bout[k2];
    }
}

// ---------------------------------------------------------------------------
// K4: Viterbi DP + backtrace. One wave per batch. Lane n (<12) owns tag `next`.
// transitions kept in registers; backpointers in LDS; feats prefetched.
// Tie-break = first max (ascending prev, strict >), matching np.argmax.
// ---------------------------------------------------------------------------
__global__ __launch_bounds__(64) void viterbi_kernel(
    const float* __restrict__ feats, const float* __restrict__ trans,
    const int* __restrict__ slen, float* __restrict__ out) {
    int b = blockIdx.x;
    int lane = threadIdx.x;
    __shared__ unsigned char bp[TLEN][KTAG];

    int len = slen[b];
    float tr[KTAG];
#pragma unroll
    for (int p = 0; p < KTAG; ++p) tr[p] = 0.f;
    if (lane < KTAG) {
#pragma unroll
        for (int p = 0; p < KTAG; ++p) tr[p] = trans[lane * KTAG + p];
    }
    float tstop = (lane < KTAG) ? trans[STOP_TAG * KTAG + lane] : NEGV;
    float dp = (lane == START_TAG) ? 0.f : NEGV;

    float ftn = (lane < KTAG) ? feats[((size_t)0 * BATCH + b) * KTAG + lane] : 0.f;
    for (int t = 0; t < TLEN; ++t) {
        float ftc = ftn;
        if (t + 1 < TLEN && lane < KTAG)
            ftn = feats[((size_t)(t + 1) * BATCH + b) * KTAG + lane];
        float best = -1e30f;
        int arg = 0;
#pragma unroll
        for (int p = 0; p < KTAG; ++p) {
            float dpp = __shfl(dp, p);
            float s = dpp + tr[p];
            if (s > best) { best = s; arg = p; }
        }
        bool m = (t < len);
        if (lane < KTAG) {
            dp = m ? (best + ftc) : dp;
            bp[t][lane] = (unsigned char)(m ? arg : lane);
        }
    }

    float term = dp + tstop;
    float bbest = -1e30f;
    int barg = 0;
#pragma unroll
    for (int p = 0; p < KTAG; ++p) {
        float v = __shfl(term, p);
        if (v > bbest) { bbest = v; barg = p; }
    }
    if (lane == 0) {
        out[b] = bbest;                     // path_scores
        float* path = out + BATCH + (size_t)b * TLEN;
        int tag = barg;
        for (int t = TLEN - 1; t >= 0; --t) {
            path[t] = (float)tag;
            tag = bp[t][tag];
        }
    }
}

// ---------------------------------------------------------------------------
extern "C" void kernel_launch(void* const* d_in, const int* in_sizes, int n_in,
                              void* d_out, int out_size, void* d_ws, size_t ws_size,
                              hipStream_t stream) {
    const int*   sentence = (const int*)d_in[0];
    const int*   slen     = (const int*)d_in[1];
    const float* emb      = (const float*)d_in[2];
    const float* Wf_ih    = (const float*)d_in[3];
    const float* Wf_hh    = (const float*)d_in[4];
    const float* bf_ih    = (const float*)d_in[5];
    const float* bf_hh    = (const float*)d_in[6];
    const float* Wb_ih    = (const float*)d_in[7];
    const float* Wb_hh    = (const float*)d_in[8];
    const float* bb_ih    = (const float*)d_in[9];
    const float* bb_hh    = (const float*)d_in[10];
    const float* W_out    = (const float*)d_in[11];
    const float* b_out    = (const float*)d_in[12];
    const float* trans    = (const float*)d_in[13];
    float* out = (float*)d_out;

    char* ws = (char*)d_ws;
    float*  xf    = (float*)(ws);                         // 134,217,728 B
    float*  xb    = (float*)(ws + 134217728ull);          // 134,217,728 B
    float*  hcat  = (float*)(ws + 268435456ull);          //  67,108,864 B
    float4* Wp    = (float4*)(ws + 335544320ull);         //   2,097,152 B
    float*  feats = (float*)(ws + 337641472ull);          //   1,572,864 B
    // total ~339.2 MB

    hipLaunchKernelGGL(pack_whh, dim3(512), dim3(256), 0, stream, Wf_hh, Wb_hh, Wp);
    hipLaunchKernelGGL(proj_kernel, dim3(256, 16), dim3(256), 0, stream,
                       sentence, emb, Wf_ih, Wb_ih, bf_ih, bf_hh, bb_ih, bb_hh, xf, xb);
    hipLaunchKernelGGL(lstm_scan, dim3(128), dim3(256), 0, stream, xf, xb, Wp, hcat);
    hipLaunchKernelGGL(feats_kernel, dim3(8192), dim3(256), 0, stream,
                       hcat, W_out, b_out, feats);
    hipLaunchKernelGGL(viterbi_kernel, dim3(64), dim3(64), 0, stream,
                       feats, trans, slen, out);
}